// Round 4
// baseline (800.855 us; speedup 1.0000x reference)
//
#include <hip/hip_runtime.h>
#include <hip/hip_bf16.h>

// DIN sequence encoder, B=4096 L=200 E=A=128, fp32 I/O, bf16 MFMA compute.
//
// v4: flash-style split. Kernel din_scores: one block per (b, 64-row chunk),
// one 16-row tile per wave, K=256 GEMM1 (att_in@W1 = qW[b] + [kp|kp*q]@[Wk;Wqk])
// + GEMM2 + score, then per-chunk online-softmax partial (m, sum_e, sum_e*kp)
// -> ws. Keys are read from HBM exactly once, with all 8 float4/lane issued
// back-to-back (MLP fix for the round-3 625 GB/s latency wall). din_combine
// merges the <=4 partials per row. No __syncthreads in the GEMM phase;
// ~37 KB LDS -> 4 blocks/CU.

typedef __attribute__((ext_vector_type(8))) short short8;
typedef __attribute__((ext_vector_type(4))) float f32x4;

__device__ __forceinline__ float bf2f(short s) {
    return __uint_as_float(((unsigned)(unsigned short)s) << 16);
}
__device__ __forceinline__ short f2bf(float f) {
    unsigned u = __float_as_uint(f);
    u = (u + 0x7fff + ((u >> 16) & 1)) >> 16;   // RNE; inputs finite
    return (short)u;
}

// ---- prep 1: fragment-ordered B blocks (bf16) into ws ----------------------
// F1[kb=sp*2+half][n][lane][j]: half0 = Wk = W1b-W1c, half1 = Wqk = W1d
//   value = B[k = 32*sp + 8*(lane>>4) + j][col = n*16 + (lane&15)]
// F2[s2][n][lane][j]: W2
__global__ void prep_frag(const float* __restrict__ W1, const float* __restrict__ W2,
                          short* __restrict__ F1, short* __restrict__ F2) {
    int idx = blockIdx.x * 256 + threadIdx.x;   // 6144 threads
    if (idx < 4096) {
        int lane = idx & 63, n = (idx >> 6) & 7, kb = idx >> 9;
        int q = lane >> 4, l15 = lane & 15;
        int sp = kb >> 1, half = kb & 1;
        int col = n * 16 + l15;
        short8 v;
        #pragma unroll
        for (int j = 0; j < 8; ++j) {
            int k = 32 * sp + 8 * q + j;
            float x = half ? W1[(384 + k) * 128 + col]
                           : W1[(128 + k) * 128 + col] - W1[(256 + k) * 128 + col];
            v[j] = f2bf(x);
        }
        *(short8*)(F1 + idx * 8) = v;
    } else if (idx < 6144) {
        int i2 = idx - 4096;
        int lane = i2 & 63, n = (i2 >> 6) & 7, s2 = i2 >> 9;
        int q = lane >> 4, l15 = lane & 15;
        int col = n * 16 + l15;
        short8 v;
        #pragma unroll
        for (int j = 0; j < 8; ++j)
            v[j] = f2bf(W2[(32 * s2 + 8 * q + j) * 128 + col]);
        *(short8*)(F2 + i2 * 8) = v;
    }
}

// ---- prep 2: qW[b][n] = b1[n] + sum_k q[b][k]*(W1a+W1c)[k][n]  (fp32) ------
__global__ void prep_qw(const float* __restrict__ query, const float* __restrict__ W1,
                        const float* __restrict__ b1, float* __restrict__ qw) {
    __shared__ float qsh[128];
    const int b = blockIdx.x, t = threadIdx.x;   // 128 threads
    qsh[t] = query[b * 128 + t];
    __syncthreads();
    float acc = b1[t];
    #pragma unroll 4
    for (int k = 0; k < 128; ++k)
        acc += qsh[k] * (W1[k * 128 + t] + W1[(256 + k) * 128 + t]);
    qw[b * 128 + t] = acc;
}

// ---- main: one block per (batch row, 64-row chunk), one tile per wave ------
#define KSTR 136  // LDS row stride in shorts: 16B-aligned, breaks pow2 banks

__launch_bounds__(256, 4)
__global__ void din_scores(const float* __restrict__ query, const float* __restrict__ keys,
                           const int* __restrict__ klen, const float* __restrict__ pos,
                           const float* __restrict__ b2g, const float* __restrict__ w3g,
                           const float* __restrict__ qw, const short* __restrict__ F1,
                           const short* __restrict__ F2,
                           float* __restrict__ Pm, float* __restrict__ Pl,
                           float* __restrict__ Po) {
    __shared__ alignas(16) short kpbuf[4 * 16 * KSTR];  // per-wave kp tiles
    __shared__ alignas(16) short h1buf[4 * 16 * KSTR];  // per-wave h1 staging
    __shared__ float w_e[64];
    __shared__ float redm[4];
    __shared__ float redl[4];
    __shared__ float part[512];

    const int t = threadIdx.x;
    const int bc = blockIdx.x;                  // b*4 + chunk
    const int b = bc >> 2, chunk = bc & 3;
    const int w = t >> 6, lane = t & 63, quad = lane >> 4, l15 = lane & 15;
    const int len = klen[b];
    const int base = chunk << 6;
    if (base >= len) {                          // whole chunk masked: cheap exit
        if (t == 0) { Pm[bc] = -1e30f; Pl[bc] = 0.f; }
        return;
    }
    const int rw = base + w * 16;               // this wave's tile start row
    const bool active = (rw < len);
    short* kpw = kpbuf + w * 16 * KSTR;
    short* h1w = h1buf + w * 16 * KSTR;

    float sv[4] = {-1e30f, -1e30f, -1e30f, -1e30f};

    if (active) {
        const int row = rw + l15;               // this lane's A-row
        // ---- all 8 HBM keys loads issued back-to-back (MLP) ----
        float4 K[8];
        if (row < 200) {
            const float4* kr = (const float4*)(keys + ((long)b * 200 + row) * 128) + quad * 2;
            #pragma unroll
            for (int s = 0; s < 4; ++s) { K[2 * s] = kr[s * 8]; K[2 * s + 1] = kr[s * 8 + 1]; }
        } else {
            #pragma unroll
            for (int j = 0; j < 8; ++j) K[j] = (float4){0.f, 0.f, 0.f, 0.f};
        }

        f32x4 acc[8];
        #pragma unroll
        for (int n = 0; n < 8; ++n) acc[n] = (f32x4){0.f, 0.f, 0.f, 0.f};

        // ---- GEMM1: K=256, A = [kp | kp*q] ----
        #pragma unroll
        for (int s = 0; s < 4; ++s) {
            short8 a;
            if (row < 200) {                    // pos is L2-resident (102 KB shared)
                const float4* pr = (const float4*)(pos + (long)row * 128) + quad * 2;
                float4 p0 = pr[s * 8], p1 = pr[s * 8 + 1];
                float4 k0 = K[2 * s], k1 = K[2 * s + 1];
                a[0] = f2bf(k0.x + p0.x); a[1] = f2bf(k0.y + p0.y);
                a[2] = f2bf(k0.z + p0.z); a[3] = f2bf(k0.w + p0.w);
                a[4] = f2bf(k1.x + p1.x); a[5] = f2bf(k1.y + p1.y);
                a[6] = f2bf(k1.z + p1.z); a[7] = f2bf(k1.w + p1.w);
            } else {
                #pragma unroll
                for (int j = 0; j < 8; ++j) a[j] = 0;
            }
            *(short8*)(kpw + l15 * KSTR + s * 32 + quad * 8) = a;   // keep for o-sum
            #pragma unroll
            for (int n = 0; n < 8; ++n) {
                short8 bf = *(const short8*)(F1 + (((2 * s) * 8 + n) * 64 + lane) * 8);
                acc[n] = __builtin_amdgcn_mfma_f32_16x16x32_bf16(a, bf, acc[n], 0, 0, 0);
            }
            float4 qa = *(const float4*)(query + b * 128 + s * 32 + quad * 8);
            float4 qb = *(const float4*)(query + b * 128 + s * 32 + quad * 8 + 4);
            short8 a2;
            a2[0] = f2bf(bf2f(a[0]) * qa.x); a2[1] = f2bf(bf2f(a[1]) * qa.y);
            a2[2] = f2bf(bf2f(a[2]) * qa.z); a2[3] = f2bf(bf2f(a[3]) * qa.w);
            a2[4] = f2bf(bf2f(a[4]) * qb.x); a2[5] = f2bf(bf2f(a[5]) * qb.y);
            a2[6] = f2bf(bf2f(a[6]) * qb.z); a2[7] = f2bf(bf2f(a[7]) * qb.w);
            #pragma unroll
            for (int n = 0; n < 8; ++n) {
                short8 bf = *(const short8*)(F1 + (((2 * s + 1) * 8 + n) * 64 + lane) * 8);
                acc[n] = __builtin_amdgcn_mfma_f32_16x16x32_bf16(a2, bf, acc[n], 0, 0, 0);
            }
        }

        // ---- h1 = relu(acc + qW): C-layout -> A-layout via own-wave LDS ----
        #pragma unroll
        for (int n = 0; n < 8; ++n) {
            float qwn = qw[b * 128 + n * 16 + l15];
            #pragma unroll
            for (int r = 0; r < 4; ++r) {
                float v = acc[n][r] + qwn;
                h1w[(quad * 4 + r) * KSTR + n * 16 + l15] = f2bf(v > 0.f ? v : 0.f);
            }
        }

        // ---- GEMM2: h1 @ W2 (K=128) ----
        #pragma unroll
        for (int n = 0; n < 8; ++n) acc[n] = (f32x4){0.f, 0.f, 0.f, 0.f};
        #pragma unroll
        for (int s2 = 0; s2 < 4; ++s2) {
            short8 a = *(const short8*)(h1w + l15 * KSTR + s2 * 32 + quad * 8);
            #pragma unroll
            for (int n = 0; n < 8; ++n) {
                short8 bf = *(const short8*)(F2 + ((s2 * 8 + n) * 64 + lane) * 8);
                acc[n] = __builtin_amdgcn_mfma_f32_16x16x32_bf16(a, bf, acc[n], 0, 0, 0);
            }
        }

        // ---- score: s = sum_n relu(h2 + b2) * W3[n]; reduce over 16 lanes ----
        float p[4] = {0.f, 0.f, 0.f, 0.f};
        #pragma unroll
        for (int n = 0; n < 8; ++n) {
            float b2n = b2g[n * 16 + l15];
            float w3n = w3g[n * 16 + l15];
            #pragma unroll
            for (int r = 0; r < 4; ++r) {
                float v = acc[n][r] + b2n;
                p[r] += (v > 0.f ? v : 0.f) * w3n;
            }
        }
        #pragma unroll
        for (int off = 8; off >= 1; off >>= 1) {
            #pragma unroll
            for (int r = 0; r < 4; ++r) p[r] += __shfl_xor(p[r], off, 64);
        }
        #pragma unroll
        for (int r = 0; r < 4; ++r)
            sv[r] = (rw + quad * 4 + r < len) ? p[r] : -1e30f;
    }

    // ---- chunk-local online-softmax partial: (M, sum_e, sum_e*kp) ----
    float m = fmaxf(fmaxf(sv[0], sv[1]), fmaxf(sv[2], sv[3]));
    m = fmaxf(m, __shfl_xor(m, 16, 64));
    m = fmaxf(m, __shfl_xor(m, 32, 64));
    if (lane == 0) redm[w] = m;
    __syncthreads();
    const float M = fmaxf(fmaxf(redm[0], redm[1]), fmaxf(redm[2], redm[3]));
    float e[4], esum = 0.f;
    #pragma unroll
    for (int r = 0; r < 4; ++r) {
        e[r] = (sv[r] > -1e29f) ? __expf(sv[r] - M) : 0.f;
        esum += e[r];
    }
    esum += __shfl_xor(esum, 16, 64);
    esum += __shfl_xor(esum, 32, 64);
    if (lane == 0) redl[w] = esum;
    if (active && l15 == 0) {
        #pragma unroll
        for (int r = 0; r < 4; ++r) w_e[w * 16 + quad * 4 + r] = e[r];
    }
    float ax = 0.f, ay = 0.f;
    if (active) {   // inactive waves contribute exact zeros (LDS is uninit there)
        #pragma unroll
        for (int j = 0; j < 16; ++j) {
            float wj = w_e[w * 16 + j];
            unsigned pr = *(const unsigned*)(kpw + j * KSTR + lane * 2);
            ax += wj * __uint_as_float(pr << 16);
            ay += wj * __uint_as_float(pr & 0xffff0000u);
        }
    }
    part[w * 128 + lane * 2]     = ax;
    part[w * 128 + lane * 2 + 1] = ay;
    __syncthreads();
    if (t < 128)
        Po[bc * 128 + t] = part[t] + part[128 + t] + part[256 + t] + part[384 + t];
    if (t == 0) {
        Pm[bc] = M;
        Pl[bc] = redl[0] + redl[1] + redl[2] + redl[3];
    }
}

// ---- combine <=4 chunk partials per batch row ------------------------------
__global__ void din_combine(const float* __restrict__ Pm, const float* __restrict__ Pl,
                            const float* __restrict__ Po, float* __restrict__ out) {
    const int b = blockIdx.x, t = threadIdx.x;   // 128 threads
    const float m0 = Pm[b * 4], m1 = Pm[b * 4 + 1], m2 = Pm[b * 4 + 2], m3 = Pm[b * 4 + 3];
    const float M = fmaxf(fmaxf(m0, m1), fmaxf(m2, m3));
    const float w0 = (m0 > -1e29f) ? __expf(m0 - M) : 0.f;
    const float w1 = (m1 > -1e29f) ? __expf(m1 - M) : 0.f;
    const float w2 = (m2 > -1e29f) ? __expf(m2 - M) : 0.f;
    const float w3 = (m3 > -1e29f) ? __expf(m3 - M) : 0.f;
    const float S = w0 * Pl[b * 4] + w1 * Pl[b * 4 + 1] + w2 * Pl[b * 4 + 2] + w3 * Pl[b * 4 + 3];
    // unwritten Po (masked chunks) is 0xAA poison = finite small float; *0 = 0.
    float o = w0 * Po[(b * 4) * 128 + t] + w1 * Po[(b * 4 + 1) * 128 + t]
            + w2 * Po[(b * 4 + 2) * 128 + t] + w3 * Po[(b * 4 + 3) * 128 + t];
    out[b * 128 + t] = o / S;
}

extern "C" void kernel_launch(void* const* d_in, const int* in_sizes, int n_in,
                              void* d_out, int out_size, void* d_ws, size_t ws_size,
                              hipStream_t stream) {
    const float* query = (const float*)d_in[0];
    const float* keys  = (const float*)d_in[1];
    const int*   klen  = (const int*)  d_in[2];
    const float* pos   = (const float*)d_in[3];
    const float* W1    = (const float*)d_in[4];
    const float* b1    = (const float*)d_in[5];
    const float* W2    = (const float*)d_in[6];
    const float* b2    = (const float*)d_in[7];
    const float* W3    = (const float*)d_in[8];
    // d_in[9] = b3: shift-invariant under softmax, unused.
    float* out = (float*)d_out;

    char* ws = (char*)d_ws;
    float* qw = (float*)ws;                            // 2 MiB
    short* F1 = (short*)(ws + 2097152);                // 64 KiB
    short* F2 = (short*)(ws + 2097152 + 65536);        // 32 KiB
    float* Pm = (float*)(ws + 2097152 + 98304);        // 64 KiB (16384 f32)
    float* Pl = (float*)(ws + 2097152 + 163840);       // 64 KiB
    float* Po = (float*)(ws + 2097152 + 229376);       // 8 MiB (16384*128 f32)

    prep_frag  <<<24,    256, 0, stream>>>(W1, W2, F1, F2);
    prep_qw    <<<4096,  128, 0, stream>>>(query, W1, b1, qw);
    din_scores <<<16384, 256, 0, stream>>>(query, keys, klen, pos, b2, W3, qw,
                                           F1, F2, Pm, Pl, Po);
    din_combine<<<4096,  128, 0, stream>>>(Pm, Pl, Po, out);
}